// Round 3
// baseline (112.818 us; speedup 1.0000x reference)
//
#include <hip/hip_runtime.h>

#define H_ 8
#define D_ 32
#define B_ 32
#define N_ 4096
#define C_ 256
#define EPS_ 1e-5f

typedef __attribute__((ext_vector_type(8))) short bf16x8;
typedef __attribute__((ext_vector_type(4))) short bf16x4;
typedef __attribute__((ext_vector_type(4))) float f32x4;

__device__ __forceinline__ short f2bf(float f) {
    unsigned u = __builtin_bit_cast(unsigned, f);
    unsigned r = (u + 0x7FFFu + ((u >> 16) & 1u)) >> 16;
    return (short)r;
}

// physical short-index of (row, col) in ubuf: 80 B row stride + 32 B shift per
// 8-row group -> fragment reads conflict-free (verified R2: 0 conflicts).
__device__ __forceinline__ int uidx(int r, int c) {
    return r * 40 + ((r >> 3) & 3) * 16 + c;
}

// ---------------------------------------------------------------------------
// Kernel 1: per (b,h) accumulate S = U^T U (32x32) and t = colsum(U) via MFMA.
// Grid: B*H*8 = 2048 blocks (512 rows each, 4 iters x 128 rows), 256 threads.
// Coalesced loads: 8 consecutive lanes share a row; LN stats via shfl_xor
// over the 8-lane group. Cross-wave S reduce in LDS -> 1024 atomics/block.
// ---------------------------------------------------------------------------
__global__ __launch_bounds__(256, 6)
void k1_skv(const float* __restrict__ x, float* __restrict__ Sws, float* __restrict__ Tws)
{
    __shared__ short ubuf[128 * 40 + 56];   // 10.4 KB; reused as float scratch

    const int tid  = threadIdx.x;
    const int bh   = blockIdx.x >> 3;
    const int q8   = blockIdx.x & 7;
    const int b    = bh >> 3;
    const int h    = bh & 7;
    const int lane = tid & 63;
    const int wave = tid >> 6;
    const int g    = lane >> 4;      // 0..3 : k-group
    const int cL   = lane & 15;      // 0..15: column within 16-block

    const int rsub = tid >> 3;       // 0..31 : row-within-32 for my chunks
    const int csub = tid & 7;        // 0..7  : float4-chunk within row

    f32x4 acc[2][2] = {};            // S quadrants [ca][cb]
    f32x4 tq[2] = {};                // column sums via ones-MFMA

    bf16x8 ones;
    #pragma unroll
    for (int j = 0; j < 8; ++j) ones[j] = (short)0x3F80;   // bf16 1.0

    const float* xbase = x + ((size_t)b * N_ + q8 * 512) * C_ + h * D_;

    // preload iter 0: chunk k -> row k*32 + rsub, cols 4*csub..+4 (coalesced:
    // 8 lanes cover one full 128B line per instruction)
    float4 xr[4];
    #pragma unroll
    for (int k = 0; k < 4; ++k)
        xr[k] = *reinterpret_cast<const float4*>(
            xbase + (size_t)(k * 32 + rsub) * C_ + csub * 4);

    for (int it = 0; it < 4; ++it) {
        // ---- LN stats per chunk: reduce over the 8-lane row group
        bf16x4 wv[4];
        #pragma unroll
        for (int k = 0; k < 4; ++k) {
            const float4 a = xr[k];
            float sum = a.x + a.y + a.z + a.w;
            float sq  = a.x * a.x + a.y * a.y + a.z * a.z + a.w * a.w;
            #pragma unroll
            for (int m = 1; m < 8; m <<= 1) {
                sum += __shfl_xor(sum, m);
                sq  += __shfl_xor(sq,  m);
            }
            const float mean = sum * (1.f / 32.f);
            const float ss   = fmaxf(sq - sum * mean, 0.f);
            const float inv  = 1.f / (sqrtf(ss * (1.f / 31.f)) + EPS_);
            wv[k][0] = f2bf((a.x - mean) * inv);
            wv[k][1] = f2bf((a.y - mean) * inv);
            wv[k][2] = f2bf((a.z - mean) * inv);
            wv[k][3] = f2bf((a.w - mean) * inv);
        }

        __syncthreads();             // prev iter's fragment reads done
        #pragma unroll
        for (int k = 0; k < 4; ++k)
            *reinterpret_cast<bf16x4*>(&ubuf[uidx(k * 32 + rsub, csub * 4)]) = wv[k];
        __syncthreads();             // writes visible

        // ---- prefetch next iter (stays in flight under MFMA phase)
        if (it < 3) {
            const float* nb = xbase + (size_t)(it + 1) * 128 * C_;
            #pragma unroll
            for (int k = 0; k < 4; ++k)
                xr[k] = *reinterpret_cast<const float4*>(
                    nb + (size_t)(k * 32 + rsub) * C_ + csub * 4);
        }

        // ---- fragment + MFMA: wave w owns K-rows [w*32, w*32+32)
        {
            const int R0 = wave * 32 + 8 * g;
            bf16x8 F0, F1;
            #pragma unroll
            for (int j = 0; j < 8; ++j) {
                const int base = uidx(R0 + j, cL);
                F0[j] = ubuf[base];
                F1[j] = ubuf[base + 16];
            }
            tq[0] = __builtin_amdgcn_mfma_f32_16x16x32_bf16(ones, F0, tq[0], 0, 0, 0);
            tq[1] = __builtin_amdgcn_mfma_f32_16x16x32_bf16(ones, F1, tq[1], 0, 0, 0);
            acc[0][0] = __builtin_amdgcn_mfma_f32_16x16x32_bf16(F0, F0, acc[0][0], 0, 0, 0);
            acc[0][1] = __builtin_amdgcn_mfma_f32_16x16x32_bf16(F0, F1, acc[0][1], 0, 0, 0);
            acc[1][0] = __builtin_amdgcn_mfma_f32_16x16x32_bf16(F1, F0, acc[1][0], 0, 0, 0);
            acc[1][1] = __builtin_amdgcn_mfma_f32_16x16x32_bf16(F1, F1, acc[1][1], 0, 0, 0);
        }
    }

    // ---- cross-wave S reduce in LDS (2 copies), then 4 atomics/thread
    // C/D layout col=lane&15, row=(lane>>4)*4+reg  [m89]
    __syncthreads();                 // last fragment reads done
    float* sred = reinterpret_cast<float*>(ubuf);
    float* dst  = sred + (wave & 1) * 1024;
    if (wave < 2) {
        #pragma unroll
        for (int ca = 0; ca < 2; ++ca)
            #pragma unroll
            for (int cb = 0; cb < 2; ++cb)
                #pragma unroll
                for (int r = 0; r < 4; ++r)
                    dst[(ca * 16 + g * 4 + r) * D_ + cb * 16 + cL] = acc[ca][cb][r];
    }
    __syncthreads();
    if (wave >= 2) {
        #pragma unroll
        for (int ca = 0; ca < 2; ++ca)
            #pragma unroll
            for (int cb = 0; cb < 2; ++cb)
                #pragma unroll
                for (int r = 0; r < 4; ++r)
                    dst[(ca * 16 + g * 4 + r) * D_ + cb * 16 + cL] += acc[ca][cb][r];
    }
    __syncthreads();
    {
        float* Sb = Sws + (size_t)bh * (D_ * D_);
        const float4 va = *reinterpret_cast<const float4*>(&sred[tid * 4]);
        const float4 vb = *reinterpret_cast<const float4*>(&sred[1024 + tid * 4]);
        atomicAdd(Sb + tid * 4 + 0, va.x + vb.x);
        atomicAdd(Sb + tid * 4 + 1, va.y + vb.y);
        atomicAdd(Sb + tid * 4 + 2, va.z + vb.z);
        atomicAdd(Sb + tid * 4 + 3, va.w + vb.w);
    }

    if (lane < 16) {                 // t: every reg holds t[col]; use reg 0
        atomicAdd(Tws + bh * D_ + cL,      tq[0][0]);
        atomicAdd(Tws + bh * D_ + 16 + cL, tq[1][0]);
    }
}

// ---------------------------------------------------------------------------
// Kernel 2: out[b,n,c] = x[b,n,c] + sum_d x[b,n,h*32+d] * kv[b,h][d][e]
// kv rebuilt from S,t with weights/biases folded in. (unchanged)
// ---------------------------------------------------------------------------
__global__ __launch_bounds__(256, 4)
void k2_out(const float* __restrict__ x,
            const float* __restrict__ Sws, const float* __restrict__ Tws,
            const float* __restrict__ kw, const float* __restrict__ kb,
            const float* __restrict__ vw, const float* __restrict__ vb,
            float* __restrict__ out)
{
    __shared__ float xbuf[4 * C_];

    const int tid   = threadIdx.x;
    const int b     = blockIdx.x >> 6;
    const int chunk = blockIdx.x & 63;
    const int h     = tid >> 5;
    const int e     = tid & 31;
    const int bh    = b * 8 + h;

    const float* S = Sws + (size_t)bh * (D_ * D_);
    const float* T = Tws + bh * D_;
    const float wve  = vw[h * D_ + e];
    const float bve  = vb[h * D_ + e];
    const float Te   = T[e];
    const float invN = 1.f / (float)N_;

    float kvc[32];
    #pragma unroll
    for (int d = 0; d < D_; ++d) {
        const float wkd = kw[h * D_ + d];
        const float bkd = kb[h * D_ + d];
        kvc[d] = invN * (wkd * (wve * S[d * D_ + e] + bve * T[d]) + bkd * wve * Te)
               + bkd * bve;
    }

    for (int it = 0; it < 16; ++it) {
        const int r0 = chunk * 64 + it * 4;
        const float* xrow = x + ((size_t)b * N_ + r0) * C_;
        const float4 xv = reinterpret_cast<const float4*>(xrow)[tid];
        __syncthreads();
        reinterpret_cast<float4*>(xbuf)[tid] = xv;
        __syncthreads();

        float res[4];
        #pragma unroll
        for (int r = 0; r < 4; ++r) {
            const float4* xr4 = reinterpret_cast<const float4*>(xbuf + r * C_ + h * D_);
            float dot = 0.f;
            #pragma unroll
            for (int c = 0; c < 8; ++c) {
                const float4 a = xr4[c];
                dot += a.x * kvc[c * 4 + 0] + a.y * kvc[c * 4 + 1]
                     + a.z * kvc[c * 4 + 2] + a.w * kvc[c * 4 + 3];
            }
            res[r] = dot + xbuf[r * C_ + tid];
        }
        float* orow = out + ((size_t)b * N_ + r0) * C_;
        #pragma unroll
        for (int r = 0; r < 4; ++r) orow[r * C_ + tid] = res[r];
    }
}

extern "C" void kernel_launch(void* const* d_in, const int* in_sizes, int n_in,
                              void* d_out, int out_size, void* d_ws, size_t ws_size,
                              hipStream_t stream)
{
    const float* x  = (const float*)d_in[0];
    const float* kw = (const float*)d_in[1];
    const float* kb = (const float*)d_in[2];
    const float* vw = (const float*)d_in[3];
    const float* vb = (const float*)d_in[4];
    float* outp = (float*)d_out;

    float* Sws = (float*)d_ws;
    float* Tws = Sws + (size_t)B_ * H_ * D_ * D_;
    const size_t zero_bytes =
        ((size_t)B_ * H_ * D_ * D_ + (size_t)B_ * H_ * D_) * sizeof(float);
    hipMemsetAsync(d_ws, 0, zero_bytes, stream);

    k1_skv<<<dim3(B_ * H_ * 8), dim3(256), 0, stream>>>(x, Sws, Tws);
    k2_out<<<dim3(B_ * 64), dim3(256), 0, stream>>>(x, Sws, Tws, kw, kb, vw, vb, outp);
}

// Round 4
// 108.339 us; speedup vs baseline: 1.0413x; 1.0413x over previous
//
#include <hip/hip_runtime.h>

#define H_ 8
#define D_ 32
#define B_ 32
#define N_ 4096
#define C_ 256
#define EPS_ 1e-5f

typedef __attribute__((ext_vector_type(8))) short bf16x8;
typedef __attribute__((ext_vector_type(4))) short bf16x4;
typedef __attribute__((ext_vector_type(4))) float f32x4;

__device__ __forceinline__ short f2bf(float f) {
    unsigned u = __builtin_bit_cast(unsigned, f);
    unsigned r = (u + 0x7FFFu + ((u >> 16) & 1u)) >> 16;
    return (short)r;
}

// physical short-index of (row, col) in ubuf: 80 B row stride + 32 B shift per
// 8-row group -> fragment reads conflict-free (verified R2: 0 conflicts).
__device__ __forceinline__ int uidx(int r, int c) {
    return r * 40 + ((r >> 3) & 3) * 16 + c;
}

// ---------------------------------------------------------------------------
// Kernel 1: per (b,h) accumulate S = U^T U (32x32) and t = colsum(U) via MFMA.
// Grid: B*H*8 = 2048 blocks (512 rows each), 256 threads.
// ALL 16 dwordx4 loads per thread issued at kernel top (deep MLP pipeline);
// 2 iters x 256-row LDS tiles (4 barriers total). 8 consecutive lanes share a
// row; LN stats via shfl_xor over the 8-lane group.
// ---------------------------------------------------------------------------
__global__ __launch_bounds__(256, 4)
void k1_skv(const float* __restrict__ x, float* __restrict__ Sws, float* __restrict__ Tws)
{
    __shared__ short ubuf[256 * 40 + 64];   // 20.6 KB; reused as float scratch

    const int tid  = threadIdx.x;
    const int bh   = blockIdx.x >> 3;
    const int q8   = blockIdx.x & 7;
    const int b    = bh >> 3;
    const int h    = bh & 7;
    const int lane = tid & 63;
    const int wave = tid >> 6;
    const int g    = lane >> 4;      // 0..3 : k-group
    const int cL   = lane & 15;      // 0..15: column within 16-block

    const int rsub = tid >> 3;       // 0..31 : row-within-32 for my chunks
    const int csub = tid & 7;        // 0..7  : float4-chunk within row

    f32x4 acc[2][2] = {};            // S quadrants [ca][cb]
    f32x4 tq[2] = {};                // column sums via ones-MFMA

    bf16x8 ones;
    #pragma unroll
    for (int j = 0; j < 8; ++j) ones[j] = (short)0x3F80;   // bf16 1.0

    const float* xbase = x + ((size_t)b * N_ + q8 * 512) * C_ + h * D_;

    // ---- issue ALL loads up front: 16 dwordx4 per thread, in consume order.
    // chunk (i,k): row = i*256 + k*32 + rsub, cols 4*csub..+4 (8 lanes = 1 line)
    float4 xr[16];
    #pragma unroll
    for (int i = 0; i < 2; ++i)
        #pragma unroll
        for (int k = 0; k < 8; ++k)
            xr[i * 8 + k] = *reinterpret_cast<const float4*>(
                xbase + (size_t)(i * 256 + k * 32 + rsub) * C_ + csub * 4);

    #pragma unroll 2
    for (int it = 0; it < 2; ++it) {
        // ---- LN stats per chunk: reduce over the 8-lane row group
        bf16x4 wv[8];
        #pragma unroll
        for (int k = 0; k < 8; ++k) {
            const float4 a = xr[it * 8 + k];
            float sum = a.x + a.y + a.z + a.w;
            float sq  = a.x * a.x + a.y * a.y + a.z * a.z + a.w * a.w;
            #pragma unroll
            for (int m = 1; m < 8; m <<= 1) {
                sum += __shfl_xor(sum, m);
                sq  += __shfl_xor(sq,  m);
            }
            const float mean = sum * (1.f / 32.f);
            const float ss   = fmaxf(sq - sum * mean, 0.f);
            const float inv  = 1.f / (sqrtf(ss * (1.f / 31.f)) + EPS_);
            wv[k][0] = f2bf((a.x - mean) * inv);
            wv[k][1] = f2bf((a.y - mean) * inv);
            wv[k][2] = f2bf((a.z - mean) * inv);
            wv[k][3] = f2bf((a.w - mean) * inv);
        }

        if (it > 0) __syncthreads();   // prev iter's fragment reads done
        #pragma unroll
        for (int k = 0; k < 8; ++k)
            *reinterpret_cast<bf16x4*>(&ubuf[uidx(k * 32 + rsub, csub * 4)]) = wv[k];
        __syncthreads();               // writes visible

        // ---- fragment + MFMA: wave w owns K-rows [w*64, w*64+64), 2 ks-steps
        #pragma unroll
        for (int ks = 0; ks < 2; ++ks) {
            const int R0 = wave * 64 + ks * 32 + 8 * g;
            bf16x8 F0, F1;
            #pragma unroll
            for (int j = 0; j < 8; ++j) {
                const int base = uidx(R0 + j, cL);
                F0[j] = ubuf[base];
                F1[j] = ubuf[base + 16];
            }
            tq[0] = __builtin_amdgcn_mfma_f32_16x16x32_bf16(ones, F0, tq[0], 0, 0, 0);
            tq[1] = __builtin_amdgcn_mfma_f32_16x16x32_bf16(ones, F1, tq[1], 0, 0, 0);
            acc[0][0] = __builtin_amdgcn_mfma_f32_16x16x32_bf16(F0, F0, acc[0][0], 0, 0, 0);
            acc[0][1] = __builtin_amdgcn_mfma_f32_16x16x32_bf16(F0, F1, acc[0][1], 0, 0, 0);
            acc[1][0] = __builtin_amdgcn_mfma_f32_16x16x32_bf16(F1, F0, acc[1][0], 0, 0, 0);
            acc[1][1] = __builtin_amdgcn_mfma_f32_16x16x32_bf16(F1, F1, acc[1][1], 0, 0, 0);
        }
    }

    // ---- cross-wave S reduce in LDS (2 copies), then 4 atomics/thread
    // C/D layout col=lane&15, row=(lane>>4)*4+reg  [m89]
    __syncthreads();                 // last fragment reads done
    float* sred = reinterpret_cast<float*>(ubuf);
    float* dst  = sred + (wave & 1) * 1024;
    if (wave < 2) {
        #pragma unroll
        for (int ca = 0; ca < 2; ++ca)
            #pragma unroll
            for (int cb = 0; cb < 2; ++cb)
                #pragma unroll
                for (int r = 0; r < 4; ++r)
                    dst[(ca * 16 + g * 4 + r) * D_ + cb * 16 + cL] = acc[ca][cb][r];
    }
    __syncthreads();
    if (wave >= 2) {
        #pragma unroll
        for (int ca = 0; ca < 2; ++ca)
            #pragma unroll
            for (int cb = 0; cb < 2; ++cb)
                #pragma unroll
                for (int r = 0; r < 4; ++r)
                    dst[(ca * 16 + g * 4 + r) * D_ + cb * 16 + cL] += acc[ca][cb][r];
    }
    __syncthreads();
    {
        float* Sb = Sws + (size_t)bh * (D_ * D_);
        const float4 va = *reinterpret_cast<const float4*>(&sred[tid * 4]);
        const float4 vb = *reinterpret_cast<const float4*>(&sred[1024 + tid * 4]);
        atomicAdd(Sb + tid * 4 + 0, va.x + vb.x);
        atomicAdd(Sb + tid * 4 + 1, va.y + vb.y);
        atomicAdd(Sb + tid * 4 + 2, va.z + vb.z);
        atomicAdd(Sb + tid * 4 + 3, va.w + vb.w);
    }

    if (lane < 16) {                 // t: every reg holds t[col]; use reg 0
        atomicAdd(Tws + bh * D_ + cL,      tq[0][0]);
        atomicAdd(Tws + bh * D_ + 16 + cL, tq[1][0]);
    }
}

// ---------------------------------------------------------------------------
// Kernel 2: out[b,n,c] = x[b,n,c] + sum_d x[b,n,h*32+d] * kv[b,h][d][e]
// kv rebuilt from S,t with weights/biases folded in. (unchanged)
// ---------------------------------------------------------------------------
__global__ __launch_bounds__(256, 4)
void k2_out(const float* __restrict__ x,
            const float* __restrict__ Sws, const float* __restrict__ Tws,
            const float* __restrict__ kw, const float* __restrict__ kb,
            const float* __restrict__ vw, const float* __restrict__ vb,
            float* __restrict__ out)
{
    __shared__ float xbuf[4 * C_];

    const int tid   = threadIdx.x;
    const int b     = blockIdx.x >> 6;
    const int chunk = blockIdx.x & 63;
    const int h     = tid >> 5;
    const int e     = tid & 31;
    const int bh    = b * 8 + h;

    const float* S = Sws + (size_t)bh * (D_ * D_);
    const float* T = Tws + bh * D_;
    const float wve  = vw[h * D_ + e];
    const float bve  = vb[h * D_ + e];
    const float Te   = T[e];
    const float invN = 1.f / (float)N_;

    float kvc[32];
    #pragma unroll
    for (int d = 0; d < D_; ++d) {
        const float wkd = kw[h * D_ + d];
        const float bkd = kb[h * D_ + d];
        kvc[d] = invN * (wkd * (wve * S[d * D_ + e] + bve * T[d]) + bkd * wve * Te)
               + bkd * bve;
    }

    for (int it = 0; it < 16; ++it) {
        const int r0 = chunk * 64 + it * 4;
        const float* xrow = x + ((size_t)b * N_ + r0) * C_;
        const float4 xv = reinterpret_cast<const float4*>(xrow)[tid];
        __syncthreads();
        reinterpret_cast<float4*>(xbuf)[tid] = xv;
        __syncthreads();

        float res[4];
        #pragma unroll
        for (int r = 0; r < 4; ++r) {
            const float4* xr4 = reinterpret_cast<const float4*>(xbuf + r * C_ + h * D_);
            float dot = 0.f;
            #pragma unroll
            for (int c = 0; c < 8; ++c) {
                const float4 a = xr4[c];
                dot += a.x * kvc[c * 4 + 0] + a.y * kvc[c * 4 + 1]
                     + a.z * kvc[c * 4 + 2] + a.w * kvc[c * 4 + 3];
            }
            res[r] = dot + xbuf[r * C_ + tid];
        }
        float* orow = out + ((size_t)b * N_ + r0) * C_;
        #pragma unroll
        for (int r = 0; r < 4; ++r) orow[r * C_ + tid] = res[r];
    }
}

extern "C" void kernel_launch(void* const* d_in, const int* in_sizes, int n_in,
                              void* d_out, int out_size, void* d_ws, size_t ws_size,
                              hipStream_t stream)
{
    const float* x  = (const float*)d_in[0];
    const float* kw = (const float*)d_in[1];
    const float* kb = (const float*)d_in[2];
    const float* vw = (const float*)d_in[3];
    const float* vb = (const float*)d_in[4];
    float* outp = (float*)d_out;

    float* Sws = (float*)d_ws;
    float* Tws = Sws + (size_t)B_ * H_ * D_ * D_;
    const size_t zero_bytes =
        ((size_t)B_ * H_ * D_ * D_ + (size_t)B_ * H_ * D_) * sizeof(float);
    hipMemsetAsync(d_ws, 0, zero_bytes, stream);

    k1_skv<<<dim3(B_ * H_ * 8), dim3(256), 0, stream>>>(x, Sws, Tws);
    k2_out<<<dim3(B_ * 64), dim3(256), 0, stream>>>(x, Sws, Tws, kw, kb, vw, vb, outp);
}